// Round 1
// baseline (6614.132 us; speedup 1.0000x reference)
//
#include <hip/hip_runtime.h>
#include <cmath>

#define DEV __device__ __forceinline__

constexpr int T_TOK   = 3072;
constexpr int D_MODEL = 1536;
constexpr int FRAMES  = 6;
constexpr int NH      = 12;
constexpr int HD      = 128;
constexpr int FF_DIM  = 8960;
constexpr int TC      = 512;
constexpr float EPS_F = 1e-6f;
constexpr float ATT_SCALE = 0.08838834764831845f; // 1/sqrt(128)

// ---------------------------------------------------------------------------
// mod[f][i][d] = modulation[i][d] + t_mod[f][i][d]
__global__ __launch_bounds__(256) void mod_kernel(
    const float* __restrict__ modulation, const float* __restrict__ t_mod,
    float* __restrict__ modbuf) {
  int i = blockIdx.x * 256 + threadIdx.x;
  if (i >= FRAMES * 6 * D_MODEL) return;
  int d  = i % D_MODEL;
  int mi = (i / D_MODEL) % 6;
  modbuf[i] = modulation[mi * D_MODEL + d] + t_mod[i];
}

// ---------------------------------------------------------------------------
DEV void block_reduce2(float& s, float& s2, float* red, int t) {
  int lane = t & 63, w = t >> 6;
#pragma unroll
  for (int o = 32; o > 0; o >>= 1) {
    s  += __shfl_down(s,  o, 64);
    s2 += __shfl_down(s2, o, 64);
  }
  if (lane == 0) { red[w] = s; red[4 + w] = s2; }
  __syncthreads();
  s  = (red[0] + red[1]) + (red[2] + red[3]);
  s2 = (red[4] + red[5]) + (red[6] + red[7]);
}

// LN (no affine) then y*(1+sc) + sh with per-frame modulation
__global__ __launch_bounds__(256) void ln_mod_kernel(
    const float* __restrict__ x, const float* __restrict__ modbuf,
    int ish, int isc, float* __restrict__ out) {
  __shared__ float red[8];
  int row = blockIdx.x, t = threadIdx.x;
  const float* xr = x + (long)row * D_MODEL;
  float vals[6];
  float s = 0.f, s2 = 0.f;
#pragma unroll
  for (int i = 0; i < 6; ++i) {
    float v = xr[t + 256 * i];
    vals[i] = v; s += v; s2 += v * v;
  }
  block_reduce2(s, s2, red, t);
  float mean = s * (1.f / D_MODEL);
  float var  = s2 * (1.f / D_MODEL) - mean * mean;
  float rs   = 1.f / sqrtf(var + EPS_F);
  const float* mb = modbuf + (long)(row >> 9) * 6 * D_MODEL;
#pragma unroll
  for (int i = 0; i < 6; ++i) {
    int d = t + 256 * i;
    float y = (vals[i] - mean) * rs;
    out[(long)row * D_MODEL + d] = y * (1.f + mb[isc * D_MODEL + d]) + mb[ish * D_MODEL + d];
  }
}

// LN with affine w,b
__global__ __launch_bounds__(256) void ln_affine_kernel(
    const float* __restrict__ x, const float* __restrict__ w,
    const float* __restrict__ b, float* __restrict__ out) {
  __shared__ float red[8];
  int row = blockIdx.x, t = threadIdx.x;
  const float* xr = x + (long)row * D_MODEL;
  float vals[6];
  float s = 0.f, s2 = 0.f;
#pragma unroll
  for (int i = 0; i < 6; ++i) {
    float v = xr[t + 256 * i];
    vals[i] = v; s += v; s2 += v * v;
  }
  block_reduce2(s, s2, red, t);
  float mean = s * (1.f / D_MODEL);
  float var  = s2 * (1.f / D_MODEL) - mean * mean;
  float rs   = 1.f / sqrtf(var + EPS_F);
#pragma unroll
  for (int i = 0; i < 6; ++i) {
    int d = t + 256 * i;
    float y = (vals[i] - mean) * rs;
    out[(long)row * D_MODEL + d] = y * w[d] + b[d];
  }
}

// In-place RMS norm (over full D) with weight, optional RoPE (per-head pairs)
template <bool ROPE>
__global__ __launch_bounds__(256) void rms_kernel(
    float* __restrict__ buf, const float* __restrict__ w,
    const float* __restrict__ cosb, const float* __restrict__ sinb) {
  __shared__ float red[8];
  int row = blockIdx.x, t = threadIdx.x;
  float* xr = buf + (long)row * D_MODEL;
  float vals[6];
  float s2 = 0.f, dummy = 0.f;
#pragma unroll
  for (int i = 0; i < 6; ++i) {
    float v = xr[t + 256 * i];
    vals[i] = v; s2 += v * v;
  }
  block_reduce2(s2, dummy, red, t);  // s2 = sum of squares (dummy unused)
  float rs = 1.f / sqrtf(s2 * (1.f / D_MODEL) + EPS_F);
  if (ROPE) {
    // 768 pairs per row; barrier in reduce already separates reads/writes
#pragma unroll
    for (int pi = 0; pi < 3; ++pi) {
      int p = t + 256 * pi;            // 0..767
      int hh = p >> 6, ii = p & 63;
      int d0 = hh * HD + 2 * ii;
      float a = xr[d0] * rs * w[d0];
      float b = xr[d0 + 1] * rs * w[d0 + 1];
      float c = cosb[(long)row * 64 + ii];
      float sn = sinb[(long)row * 64 + ii];
      xr[d0]     = a * c - b * sn;
      xr[d0 + 1] = a * sn + b * c;
    }
  } else {
#pragma unroll
    for (int i = 0; i < 6; ++i) {
      int d = t + 256 * i;
      xr[d] = vals[i] * rs * w[d];
    }
  }
}

// ---------------------------------------------------------------------------
// Generic fp32 GEMM: C[M,N] = epi(A[M,K] @ B[K,N] + bias)
// EPI: 0=bias, 1=gelu(bias), 2=res + (acc+bias)*mod_gate, 3=res + acc + bias
template <int EPI>
__global__ __launch_bounds__(256) void gemm128_kernel(
    const float* __restrict__ A, const float* __restrict__ B,
    const float* __restrict__ bias, const float* __restrict__ res,
    const float* __restrict__ modbuf, int gidx, int row0,
    float* __restrict__ C, int M, int N, int K) {
  __shared__ float As[16][132];
  __shared__ float Bs[16][132];
  const int t = threadIdx.x;
  const int bm = blockIdx.y * 128, bn = blockIdx.x * 128;
  const int ty = t >> 4, tx = t & 15;
  float acc[8][8];
#pragma unroll
  for (int i = 0; i < 8; ++i)
#pragma unroll
    for (int j = 0; j < 8; ++j) acc[i][j] = 0.f;

  const int arow = t >> 1, akq = (t & 1) * 8;
  const int brow = t >> 5, bcol = (t & 31) * 4;
  const float* Ap = A + (long)(bm + arow) * K + akq;
  const float* Bp = B + (long)brow * N + bn + bcol;

  for (int k0 = 0; k0 < K; k0 += 16) {
    float4 av0 = *(const float4*)(Ap + k0);
    float4 av1 = *(const float4*)(Ap + k0 + 4);
    float4 bv0 = *(const float4*)(Bp + (long)k0 * N);
    float4 bv1 = *(const float4*)(Bp + (long)(k0 + 8) * N);
    __syncthreads();
    As[akq + 0][arow] = av0.x; As[akq + 1][arow] = av0.y;
    As[akq + 2][arow] = av0.z; As[akq + 3][arow] = av0.w;
    As[akq + 4][arow] = av1.x; As[akq + 5][arow] = av1.y;
    As[akq + 6][arow] = av1.z; As[akq + 7][arow] = av1.w;
    *(float4*)&Bs[brow][bcol]     = bv0;
    *(float4*)&Bs[brow + 8][bcol] = bv1;
    __syncthreads();
#pragma unroll
    for (int kk = 0; kk < 16; ++kk) {
      float a[8], b[8];
      *(float4*)&a[0] = *(const float4*)&As[kk][ty * 4];
      *(float4*)&a[4] = *(const float4*)&As[kk][64 + ty * 4];
      *(float4*)&b[0] = *(const float4*)&Bs[kk][tx * 4];
      *(float4*)&b[4] = *(const float4*)&Bs[kk][64 + tx * 4];
#pragma unroll
      for (int i = 0; i < 8; ++i)
#pragma unroll
        for (int j = 0; j < 8; ++j) acc[i][j] = fmaf(a[i], b[j], acc[i][j]);
    }
  }

#pragma unroll
  for (int i = 0; i < 8; ++i) {
    int r = bm + ((i >> 2) << 6) + ty * 4 + (i & 3);
    long rowoff = (long)r * N;
    const float* mrow = nullptr;
    if (EPI == 2) {
      int f = (row0 + r) >> 9;
      mrow = modbuf + (long)(f * 6 + gidx) * D_MODEL;
    }
#pragma unroll
    for (int jj = 0; jj < 2; ++jj) {
      int c0 = bn + (jj << 6) + tx * 4;
      float tmp[4];
#pragma unroll
      for (int m = 0; m < 4; ++m) {
        int c = c0 + m;
        float val = acc[i][jj * 4 + m] + bias[c];
        if (EPI == 1) {
          float u = val;
          val = 0.5f * u * (1.f + tanhf(0.7978845608028654f * (u + 0.044715f * u * u * u)));
        } else if (EPI == 2) {
          val = res[rowoff + c] + val * mrow[c];
        } else if (EPI == 3) {
          val = res[rowoff + c] + val;
        }
        tmp[m] = val;
      }
      *(float4*)&C[rowoff + c0] = *(float4*)tmp;
    }
  }
}

// 64x64 tile variant for small-M GEMMs (bias epilogue only)
__global__ __launch_bounds__(256) void gemm64_kernel(
    const float* __restrict__ A, const float* __restrict__ B,
    const float* __restrict__ bias, float* __restrict__ C,
    int M, int N, int K) {
  __shared__ float As[16][68];
  __shared__ float Bs[16][68];
  const int t = threadIdx.x;
  const int bm = blockIdx.y * 64, bn = blockIdx.x * 64;
  const int ty = t >> 4, tx = t & 15;
  float acc[4][4];
#pragma unroll
  for (int i = 0; i < 4; ++i)
#pragma unroll
    for (int j = 0; j < 4; ++j) acc[i][j] = 0.f;

  const int arow = t >> 2, akq = (t & 3) * 4;
  const int brow = t >> 4, bcol = (t & 15) * 4;
  const float* Ap = A + (long)(bm + arow) * K + akq;
  const float* Bp = B + (long)brow * N + bn + bcol;

  for (int k0 = 0; k0 < K; k0 += 16) {
    float4 av = *(const float4*)(Ap + k0);
    float4 bv = *(const float4*)(Bp + (long)k0 * N);
    __syncthreads();
    As[akq + 0][arow] = av.x; As[akq + 1][arow] = av.y;
    As[akq + 2][arow] = av.z; As[akq + 3][arow] = av.w;
    *(float4*)&Bs[brow][bcol] = bv;
    __syncthreads();
#pragma unroll
    for (int kk = 0; kk < 16; ++kk) {
      float a[4], b[4];
      *(float4*)&a[0] = *(const float4*)&As[kk][ty * 4];
      *(float4*)&b[0] = *(const float4*)&Bs[kk][tx * 4];
#pragma unroll
      for (int i = 0; i < 4; ++i)
#pragma unroll
        for (int j = 0; j < 4; ++j) acc[i][j] = fmaf(a[i], b[j], acc[i][j]);
    }
  }
#pragma unroll
  for (int i = 0; i < 4; ++i) {
    int r = bm + ty * 4 + i;
    long rowoff = (long)r * N;
    int c0 = bn + tx * 4;
    float tmp[4];
#pragma unroll
    for (int m = 0; m < 4; ++m) tmp[m] = acc[i][m] + bias[c0 + m];
    *(float4*)&C[rowoff + c0] = *(float4*)tmp;
  }
}

// ---------------------------------------------------------------------------
// Flash-style attention. q:(T,NH*HD) k,v:(Tk,NH*HD), frame-causal when CAUSAL.
// Block: 32 q-rows for one head. Tiles of 64 k-rows.
template <bool CAUSAL>
__global__ __launch_bounds__(256) void attn_kernel(
    const float* __restrict__ q, const float* __restrict__ k,
    const float* __restrict__ v, float* __restrict__ o, int Tk) {
  __shared__ float Qs[32][132];
  __shared__ float Ks[64][132];
  __shared__ float Ss[32][65];
  const int t  = threadIdx.x;
  const int h  = blockIdx.y;
  const int q0 = blockIdx.x * 32;

#pragma unroll
  for (int i = 0; i < 4; ++i) {
    int idx = t + 256 * i;
    int r = idx >> 5, c4 = (idx & 31) * 4;
    *(float4*)&Qs[r][c4] = *(const float4*)&q[(long)(q0 + r) * D_MODEL + h * HD + c4];
  }

  const int kmax = CAUSAL ? (((q0 >> 9) + 1) << 9) : Tk;
  const int pr = t >> 3;            // PV/softmax row
  const int pc = (t & 7) * 4;       // PV col base (stride-32 groups)
  const int kbase = (t & 7) * 8;    // P-write slice
  const int tr = t >> 4, tc = t & 15;

  float m_run = -1e30f, l_run = 0.f;
  float pacc[4][4];
#pragma unroll
  for (int jj = 0; jj < 4; ++jj)
#pragma unroll
    for (int m = 0; m < 4; ++m) pacc[jj][m] = 0.f;

  for (int k0 = 0; k0 < kmax; k0 += 64) {
    __syncthreads();  // prev PV done with Ks/Ss
#pragma unroll
    for (int i = 0; i < 8; ++i) {
      int idx = t + 256 * i;
      int r = idx >> 5, c4 = (idx & 31) * 4;
      *(float4*)&Ks[r][c4] = *(const float4*)&k[(long)(k0 + r) * D_MODEL + h * HD + c4];
    }
    __syncthreads();
    // S tile: rows {tr, tr+16}, cols {tc+16j}
    float sacc[2][4] = {{0, 0, 0, 0}, {0, 0, 0, 0}};
#pragma unroll
    for (int kk = 0; kk < HD; kk += 4) {
      float4 a0 = *(const float4*)&Qs[tr][kk];
      float4 a1 = *(const float4*)&Qs[tr + 16][kk];
#pragma unroll
      for (int j = 0; j < 4; ++j) {
        float4 bb = *(const float4*)&Ks[tc + 16 * j][kk];
        sacc[0][j] = fmaf(a0.x, bb.x, sacc[0][j]);
        sacc[0][j] = fmaf(a0.y, bb.y, sacc[0][j]);
        sacc[0][j] = fmaf(a0.z, bb.z, sacc[0][j]);
        sacc[0][j] = fmaf(a0.w, bb.w, sacc[0][j]);
        sacc[1][j] = fmaf(a1.x, bb.x, sacc[1][j]);
        sacc[1][j] = fmaf(a1.y, bb.y, sacc[1][j]);
        sacc[1][j] = fmaf(a1.z, bb.z, sacc[1][j]);
        sacc[1][j] = fmaf(a1.w, bb.w, sacc[1][j]);
      }
    }
#pragma unroll
    for (int i = 0; i < 2; ++i)
#pragma unroll
      for (int j = 0; j < 4; ++j)
        Ss[tr + 16 * i][tc + 16 * j] = sacc[i][j] * ATT_SCALE;
    __syncthreads();  // S written; Ks reads done
    // V tile load (overwrites K) overlapped with softmax scan of raw S
#pragma unroll
    for (int i = 0; i < 8; ++i) {
      int idx = t + 256 * i;
      int r = idx >> 5, c4 = (idx & 31) * 4;
      *(float4*)&Ks[r][c4] = *(const float4*)&v[(long)(k0 + r) * D_MODEL + h * HD + c4];
    }
    float m4[4] = {-1e30f, -1e30f, -1e30f, -1e30f};
#pragma unroll
    for (int kk = 0; kk < 64; kk += 4) {
      m4[0] = fmaxf(m4[0], Ss[pr][kk]);
      m4[1] = fmaxf(m4[1], Ss[pr][kk + 1]);
      m4[2] = fmaxf(m4[2], Ss[pr][kk + 2]);
      m4[3] = fmaxf(m4[3], Ss[pr][kk + 3]);
    }
    float mt = fmaxf(fmaxf(m4[0], m4[1]), fmaxf(m4[2], m4[3]));
    float mnew  = fmaxf(m_run, mt);
    float alpha = __expf(m_run - mnew);
    float ps[4] = {0, 0, 0, 0};
#pragma unroll
    for (int kk = 0; kk < 64; kk += 4) {
      ps[0] += __expf(Ss[pr][kk] - mnew);
      ps[1] += __expf(Ss[pr][kk + 1] - mnew);
      ps[2] += __expf(Ss[pr][kk + 2] - mnew);
      ps[3] += __expf(Ss[pr][kk + 3] - mnew);
    }
    float psum = (ps[0] + ps[1]) + (ps[2] + ps[3]);
    float p8[8];
#pragma unroll
    for (int m2 = 0; m2 < 8; ++m2) p8[m2] = __expf(Ss[pr][kbase + m2] - mnew);
    l_run = l_run * alpha + psum;
    m_run = mnew;
#pragma unroll
    for (int jj = 0; jj < 4; ++jj)
#pragma unroll
      for (int m = 0; m < 4; ++m) pacc[jj][m] *= alpha;
    __syncthreads();  // all raw-S reads done; V writes done
#pragma unroll
    for (int m2 = 0; m2 < 8; ++m2) Ss[pr][kbase + m2] = p8[m2];
    __syncthreads();  // P ready
#pragma unroll 8
    for (int kk = 0; kk < 64; ++kk) {
      float p = Ss[pr][kk];
#pragma unroll
      for (int jj = 0; jj < 4; ++jj) {
        float4 vv = *(const float4*)&Ks[kk][pc + 32 * jj];
        pacc[jj][0] = fmaf(p, vv.x, pacc[jj][0]);
        pacc[jj][1] = fmaf(p, vv.y, pacc[jj][1]);
        pacc[jj][2] = fmaf(p, vv.z, pacc[jj][2]);
        pacc[jj][3] = fmaf(p, vv.w, pacc[jj][3]);
      }
    }
  }
  float inv = 1.f / l_run;
  long obase = (long)(q0 + pr) * D_MODEL + h * HD;
#pragma unroll
  for (int jj = 0; jj < 4; ++jj) {
    float tmp[4];
#pragma unroll
    for (int m = 0; m < 4; ++m) tmp[m] = pacc[jj][m] * inv;
    *(float4*)&o[obase + pc + 32 * jj] = *(float4*)tmp;
  }
}

// ---------------------------------------------------------------------------
extern "C" void kernel_launch(void* const* d_in, const int* in_sizes, int n_in,
                              void* d_out, int out_size, void* d_ws, size_t ws_size,
                              hipStream_t stream) {
  const float* x      = (const float*)d_in[0];
  const float* ctx    = (const float*)d_in[1];
  const float* t_mod  = (const float*)d_in[2];
  const float* fcos   = (const float*)d_in[3];
  const float* fsin   = (const float*)d_in[4];
  const float* sa_wq = (const float*)d_in[5];  const float* sa_bq = (const float*)d_in[6];
  const float* sa_wk = (const float*)d_in[7];  const float* sa_bk = (const float*)d_in[8];
  const float* sa_wv = (const float*)d_in[9];  const float* sa_bv = (const float*)d_in[10];
  const float* sa_wo = (const float*)d_in[11]; const float* sa_bo = (const float*)d_in[12];
  const float* sa_nq = (const float*)d_in[13]; const float* sa_nk = (const float*)d_in[14];
  const float* ca_wq = (const float*)d_in[15]; const float* ca_bq = (const float*)d_in[16];
  const float* ca_wk = (const float*)d_in[17]; const float* ca_bk = (const float*)d_in[18];
  const float* ca_wv = (const float*)d_in[19]; const float* ca_bv = (const float*)d_in[20];
  const float* ca_wo = (const float*)d_in[21]; const float* ca_bo = (const float*)d_in[22];
  const float* ca_nq = (const float*)d_in[23]; const float* ca_nk = (const float*)d_in[24];
  const float* n3w = (const float*)d_in[25]; const float* n3b = (const float*)d_in[26];
  const float* w1 = (const float*)d_in[27]; const float* b1 = (const float*)d_in[28];
  const float* w2 = (const float*)d_in[29]; const float* b2 = (const float*)d_in[30];
  const float* modulation = (const float*)d_in[31];
  (void)in_sizes; (void)n_in; (void)out_size; (void)ws_size;

  float* out = (float*)d_out;
  float* ws  = (float*)d_ws;
  const long TD = (long)T_TOK * D_MODEL;

  float* modbuf = ws;
  float* inp  = modbuf + FRAMES * 6 * D_MODEL;
  float* qb   = inp + TD;
  float* kb   = qb + TD;
  float* vb   = kb + TD;
  float* att  = vb + TD;
  float* x1   = att + TD;
  float* x2   = x1 + TD;
  float* hbuf = x2 + TD;  // CH * FF_DIM

  dim3 b256(256);
  dim3 gT(T_TOK);
  dim3 g128(D_MODEL / 128, T_TOK / 128);
  dim3 gattn(T_TOK / 32, NH);

  // modulation precompute
  mod_kernel<<<dim3((FRAMES * 6 * D_MODEL + 255) / 256), b256, 0, stream>>>(modulation, t_mod, modbuf);

  // ===== self-attention branch =====
  ln_mod_kernel<<<gT, b256, 0, stream>>>(x, modbuf, 0, 1, inp);
  gemm128_kernel<0><<<g128, b256, 0, stream>>>(inp, sa_wq, sa_bq, nullptr, nullptr, 0, 0, qb, T_TOK, D_MODEL, D_MODEL);
  gemm128_kernel<0><<<g128, b256, 0, stream>>>(inp, sa_wk, sa_bk, nullptr, nullptr, 0, 0, kb, T_TOK, D_MODEL, D_MODEL);
  gemm128_kernel<0><<<g128, b256, 0, stream>>>(inp, sa_wv, sa_bv, nullptr, nullptr, 0, 0, vb, T_TOK, D_MODEL, D_MODEL);
  rms_kernel<true><<<gT, b256, 0, stream>>>(qb, sa_nq, fcos, fsin);
  rms_kernel<true><<<gT, b256, 0, stream>>>(kb, sa_nk, fcos, fsin);
  attn_kernel<true><<<gattn, b256, 0, stream>>>(qb, kb, vb, att, T_TOK);
  gemm128_kernel<2><<<g128, b256, 0, stream>>>(att, sa_wo, sa_bo, x, modbuf, 2, 0, x1, T_TOK, D_MODEL, D_MODEL);

  // ===== cross-attention branch =====
  ln_affine_kernel<<<gT, b256, 0, stream>>>(x1, n3w, n3b, inp);
  gemm128_kernel<0><<<g128, b256, 0, stream>>>(inp, ca_wq, ca_bq, nullptr, nullptr, 0, 0, qb, T_TOK, D_MODEL, D_MODEL);
  rms_kernel<false><<<gT, b256, 0, stream>>>(qb, ca_nq, nullptr, nullptr);
  dim3 g64c(D_MODEL / 64, TC / 64);
  gemm64_kernel<<<g64c, b256, 0, stream>>>(ctx, ca_wk, ca_bk, kb, TC, D_MODEL, D_MODEL);
  rms_kernel<false><<<dim3(TC), b256, 0, stream>>>(kb, ca_nk, nullptr, nullptr);
  gemm64_kernel<<<g64c, b256, 0, stream>>>(ctx, ca_wv, ca_bv, vb, TC, D_MODEL, D_MODEL);
  attn_kernel<false><<<gattn, b256, 0, stream>>>(qb, kb, vb, att, TC);
  gemm128_kernel<3><<<g128, b256, 0, stream>>>(att, ca_wo, ca_bo, x1, nullptr, 0, 0, x2, T_TOK, D_MODEL, D_MODEL);

  // ===== MLP branch =====
  ln_mod_kernel<<<gT, b256, 0, stream>>>(x2, modbuf, 3, 4, inp);
  constexpr int CH = 1536;  // row-chunk (multiple of 512 frame size)
  for (int c = 0; c < T_TOK / CH; ++c) {
    const float* inpc = inp + (long)c * CH * D_MODEL;
    gemm128_kernel<1><<<dim3(FF_DIM / 128, CH / 128), b256, 0, stream>>>(
        inpc, w1, b1, nullptr, nullptr, 0, 0, hbuf, CH, FF_DIM, D_MODEL);
    gemm128_kernel<2><<<dim3(D_MODEL / 128, CH / 128), b256, 0, stream>>>(
        hbuf, w2, b2, x2 + (long)c * CH * D_MODEL, modbuf, 5, c * CH,
        out + (long)c * CH * D_MODEL, CH, D_MODEL, FF_DIM);
  }
}

// Round 2
// 2180.253 us; speedup vs baseline: 3.0337x; 3.0337x over previous
//
#include <hip/hip_runtime.h>
#include <cmath>

#define DEV __device__ __forceinline__

constexpr int T_TOK   = 3072;
constexpr int D_MODEL = 1536;
constexpr int FRAMES  = 6;
constexpr int NH      = 12;
constexpr int HD      = 128;
constexpr int FF_DIM  = 8960;
constexpr int TC      = 512;
constexpr float EPS_F = 1e-6f;
constexpr float ATT_SCALE = 0.08838834764831845f; // 1/sqrt(128)

typedef short bf16x8 __attribute__((ext_vector_type(8)));
typedef float f32x4  __attribute__((ext_vector_type(4)));

DEV ushort f2bf(float f) {
  unsigned u = __builtin_bit_cast(unsigned, f);
  unsigned r = u + 0x7fff + ((u >> 16) & 1);
  return (ushort)(r >> 16);
}

DEV void gload16(const void* g, void* l) {
  __builtin_amdgcn_global_load_lds(
      (const __attribute__((address_space(1))) void*)g,
      (__attribute__((address_space(3))) void*)l, 16, 0, 0);
}

// ---------------------------------------------------------------------------
__global__ __launch_bounds__(256) void mod_kernel(
    const float* __restrict__ modulation, const float* __restrict__ t_mod,
    float* __restrict__ modbuf) {
  int i = blockIdx.x * 256 + threadIdx.x;
  if (i >= FRAMES * 6 * D_MODEL) return;
  int d  = i % D_MODEL;
  int mi = (i / D_MODEL) % 6;
  modbuf[i] = modulation[mi * D_MODEL + d] + t_mod[i];
}

// fp32 -> bf16 elementwise (n4 = count/4)
__global__ __launch_bounds__(256) void cvt_bf16_kernel(
    const float* __restrict__ in, ushort* __restrict__ out, int n4) {
  int i = blockIdx.x * 256 + threadIdx.x;
  if (i >= n4) return;
  float4 v = ((const float4*)in)[i];
  ushort4 o;
  o.x = f2bf(v.x); o.y = f2bf(v.y); o.z = f2bf(v.z); o.w = f2bf(v.w);
  ((ushort4*)out)[i] = o;
}

// W(K,N) fp32 -> Wt(N,K) bf16. grid (N/64, K/64), block 256.
__global__ __launch_bounds__(256) void wconv_kernel(
    const float* __restrict__ W, ushort* __restrict__ Wt, int K, int N) {
  __shared__ float tile[64][65];
  const int k0 = blockIdx.y * 64, n0 = blockIdx.x * 64;
  const int t = threadIdx.x;
  const int r = t >> 4, c4 = (t & 15) * 4;
#pragma unroll
  for (int i = 0; i < 4; ++i) {
    float4 v = *(const float4*)&W[(long)(k0 + r + 16 * i) * N + n0 + c4];
    tile[r + 16 * i][c4 + 0] = v.x; tile[r + 16 * i][c4 + 1] = v.y;
    tile[r + 16 * i][c4 + 2] = v.z; tile[r + 16 * i][c4 + 3] = v.w;
  }
  __syncthreads();
  const int orow = t >> 5, oc2 = (t & 31) * 2;
#pragma unroll
  for (int j = 0; j < 8; ++j) {
    int nrow = orow + 8 * j;
    ushort2 o;
    o.x = f2bf(tile[oc2][nrow]);
    o.y = f2bf(tile[oc2 + 1][nrow]);
    *(ushort2*)&Wt[(long)(n0 + nrow) * K + k0 + oc2] = o;
  }
}

// ---------------------------------------------------------------------------
DEV void block_reduce2(float& s, float& s2, float* red, int t) {
  int lane = t & 63, w = t >> 6;
#pragma unroll
  for (int o = 32; o > 0; o >>= 1) {
    s  += __shfl_down(s,  o, 64);
    s2 += __shfl_down(s2, o, 64);
  }
  if (lane == 0) { red[w] = s; red[4 + w] = s2; }
  __syncthreads();
  s  = (red[0] + red[1]) + (red[2] + red[3]);
  s2 = (red[4] + red[5]) + (red[6] + red[7]);
}

// LN (no affine) then y*(1+sc)+sh, bf16 output
__global__ __launch_bounds__(256) void ln_mod_kernel(
    const float* __restrict__ x, const float* __restrict__ modbuf,
    int ish, int isc, ushort* __restrict__ out) {
  __shared__ float red[8];
  int row = blockIdx.x, t = threadIdx.x;
  const float* xr = x + (long)row * D_MODEL;
  float vals[6];
  float s = 0.f, s2 = 0.f;
#pragma unroll
  for (int i = 0; i < 6; ++i) {
    float v = xr[t + 256 * i];
    vals[i] = v; s += v; s2 += v * v;
  }
  block_reduce2(s, s2, red, t);
  float mean = s * (1.f / D_MODEL);
  float var  = s2 * (1.f / D_MODEL) - mean * mean;
  float rs   = 1.f / sqrtf(var + EPS_F);
  const float* mb = modbuf + (long)(row >> 9) * 6 * D_MODEL;
#pragma unroll
  for (int i = 0; i < 6; ++i) {
    int d = t + 256 * i;
    float y = (vals[i] - mean) * rs;
    out[(long)row * D_MODEL + d] = f2bf(y * (1.f + mb[isc * D_MODEL + d]) + mb[ish * D_MODEL + d]);
  }
}

// LN with affine w,b, bf16 output
__global__ __launch_bounds__(256) void ln_affine_kernel(
    const float* __restrict__ x, const float* __restrict__ w,
    const float* __restrict__ b, ushort* __restrict__ out) {
  __shared__ float red[8];
  int row = blockIdx.x, t = threadIdx.x;
  const float* xr = x + (long)row * D_MODEL;
  float vals[6];
  float s = 0.f, s2 = 0.f;
#pragma unroll
  for (int i = 0; i < 6; ++i) {
    float v = xr[t + 256 * i];
    vals[i] = v; s += v; s2 += v * v;
  }
  block_reduce2(s, s2, red, t);
  float mean = s * (1.f / D_MODEL);
  float var  = s2 * (1.f / D_MODEL) - mean * mean;
  float rs   = 1.f / sqrtf(var + EPS_F);
#pragma unroll
  for (int i = 0; i < 6; ++i) {
    int d = t + 256 * i;
    float y = (vals[i] - mean) * rs;
    out[(long)row * D_MODEL + d] = f2bf(y * w[d] + b[d]);
  }
}

// In-place fp32 RMS norm over D, optional RoPE; strided rows
template <bool ROPE>
__global__ __launch_bounds__(256) void rms_kernel(
    float* __restrict__ buf, int stride, const float* __restrict__ w,
    const float* __restrict__ cosb, const float* __restrict__ sinb) {
  __shared__ float red[8];
  int row = blockIdx.x, t = threadIdx.x;
  float* xr = buf + (long)row * stride;
  float vals[6];
  float s2 = 0.f, dummy = 0.f;
#pragma unroll
  for (int i = 0; i < 6; ++i) {
    float v = xr[t + 256 * i];
    vals[i] = v; s2 += v * v;
  }
  block_reduce2(s2, dummy, red, t);
  float rs = 1.f / sqrtf(s2 * (1.f / D_MODEL) + EPS_F);
  if (ROPE) {
#pragma unroll
    for (int pi = 0; pi < 3; ++pi) {
      int p = t + 256 * pi;            // 0..767
      int hh = p >> 6, ii = p & 63;
      int d0 = hh * HD + 2 * ii;
      float a = xr[d0] * rs * w[d0];
      float b = xr[d0 + 1] * rs * w[d0 + 1];
      float c = cosb[(long)row * 64 + ii];
      float sn = sinb[(long)row * 64 + ii];
      xr[d0]     = a * c - b * sn;
      xr[d0 + 1] = a * sn + b * c;
    }
  } else {
#pragma unroll
    for (int i = 0; i < 6; ++i) {
      int d = t + 256 * i;
      xr[d] = vals[i] * rs * w[d];
    }
  }
}

// ---------------------------------------------------------------------------
// bf16 MFMA GEMM (m97 structure): C[M,N] = epi(A[M,K] @ Bt[N,K]^T + bias)
// A,Bt bf16 row-major; 128x128 tile, BK=32, 4 waves (2x2), 64x64 per wave.
// EPI: 0 = bias -> fp32 out
//      1 = gelu(bias) -> bf16 out
//      2 = res + (acc+bias)*mod_gate -> fp32 out
//      3 = res + acc + bias -> fp32 out
template <int EPI>
__global__ __launch_bounds__(256) void mgemm_kernel(
    const ushort* __restrict__ A, const ushort* __restrict__ Bt,
    const float* __restrict__ bias, const float* __restrict__ res,
    const float* __restrict__ modbuf, int gidx,
    void* __restrict__ Cout, int M, int N, int K, int ldc) {
  __shared__ ushort As[128 * 32];
  __shared__ ushort Bs[128 * 32];
  const int t = threadIdx.x;
  const int bm = blockIdx.y * 128, bn = blockIdx.x * 128;
  const int wave = t >> 6, lane = t & 63;
  const int wr = (wave >> 1) * 64, wc = (wave & 1) * 64;
  const int l15 = lane & 15, l4 = lane >> 4;

  f32x4 acc[4][4] = {};

  const int srow  = t >> 2;         // 0..63
  const int skoff = (t & 3) * 8;    // 0,8,16,24
  const ushort* Ag = A  + (long)(bm + srow) * K + skoff;
  const ushort* Bg = Bt + (long)(bn + srow) * K + skoff;
  ushort* Asl = As + t * 8;
  ushort* Bsl = Bs + t * 8;
  const long half = (long)64 * K;

  for (int k0 = 0; k0 < K; k0 += 32) {
    __syncthreads();
    gload16(Ag + k0, Asl);
    gload16(Ag + k0 + half, Asl + 2048);
    gload16(Bg + k0, Bsl);
    gload16(Bg + k0 + half, Bsl + 2048);
    asm volatile("s_waitcnt vmcnt(0)" ::: "memory");
    __syncthreads();
    bf16x8 af[4], bfr[4];
#pragma unroll
    for (int m = 0; m < 4; ++m)
      af[m] = *(const bf16x8*)&As[(wr + m * 16 + l15) * 32 + l4 * 8];
#pragma unroll
    for (int n = 0; n < 4; ++n)
      bfr[n] = *(const bf16x8*)&Bs[(wc + n * 16 + l15) * 32 + l4 * 8];
#pragma unroll
    for (int m = 0; m < 4; ++m)
#pragma unroll
      for (int n = 0; n < 4; ++n)
        acc[m][n] = __builtin_amdgcn_mfma_f32_16x16x32_bf16(af[m], bfr[n], acc[m][n], 0, 0, 0);
  }

#pragma unroll
  for (int m = 0; m < 4; ++m) {
#pragma unroll
    for (int r = 0; r < 4; ++r) {
      const int grow = bm + wr + m * 16 + l4 * 4 + r;
      const long rowoff = (long)grow * ldc;
      const float* mrow = nullptr;
      if (EPI == 2) mrow = modbuf + (long)((grow >> 9) * 6 + gidx) * D_MODEL;
#pragma unroll
      for (int n = 0; n < 4; ++n) {
        const int gcol = bn + wc + n * 16 + l15;
        float val = acc[m][n][r] + bias[gcol];
        if (EPI == 0) {
          ((float*)Cout)[rowoff + gcol] = val;
        } else if (EPI == 1) {
          float u = val;
          val = 0.5f * u * (1.f + tanhf(0.7978845608028654f * (u + 0.044715f * u * u * u)));
          ((ushort*)Cout)[rowoff + gcol] = f2bf(val);
        } else if (EPI == 2) {
          ((float*)Cout)[rowoff + gcol] = res[rowoff + gcol] + val * mrow[gcol];
        } else {
          ((float*)Cout)[rowoff + gcol] = res[rowoff + gcol] + val;
        }
      }
    }
  }
}

// ---------------------------------------------------------------------------
// fp32 flash attention, strided q/k/v, bf16 output (stride D_MODEL).
template <bool CAUSAL>
__global__ __launch_bounds__(256) void attn_kernel(
    const float* __restrict__ q, int qs, const float* __restrict__ k, int ks,
    const float* __restrict__ v, int vs, ushort* __restrict__ o, int Tk) {
  __shared__ float Qs[32][132];
  __shared__ float Ks[64][132];
  __shared__ float Ss[32][65];
  const int t  = threadIdx.x;
  const int h  = blockIdx.y;
  const int q0 = blockIdx.x * 32;

#pragma unroll
  for (int i = 0; i < 4; ++i) {
    int idx = t + 256 * i;
    int r = idx >> 5, c4 = (idx & 31) * 4;
    *(float4*)&Qs[r][c4] = *(const float4*)&q[(long)(q0 + r) * qs + h * HD + c4];
  }

  const int kmax = CAUSAL ? (((q0 >> 9) + 1) << 9) : Tk;
  const int pr = t >> 3;
  const int pc = (t & 7) * 4;
  const int kbase = (t & 7) * 8;
  const int tr = t >> 4, tc = t & 15;

  float m_run = -1e30f, l_run = 0.f;
  float pacc[4][4];
#pragma unroll
  for (int jj = 0; jj < 4; ++jj)
#pragma unroll
    for (int m = 0; m < 4; ++m) pacc[jj][m] = 0.f;

  for (int k0 = 0; k0 < kmax; k0 += 64) {
    __syncthreads();
#pragma unroll
    for (int i = 0; i < 8; ++i) {
      int idx = t + 256 * i;
      int r = idx >> 5, c4 = (idx & 31) * 4;
      *(float4*)&Ks[r][c4] = *(const float4*)&k[(long)(k0 + r) * ks + h * HD + c4];
    }
    __syncthreads();
    float sacc[2][4] = {{0, 0, 0, 0}, {0, 0, 0, 0}};
#pragma unroll
    for (int kk = 0; kk < HD; kk += 4) {
      float4 a0 = *(const float4*)&Qs[tr][kk];
      float4 a1 = *(const float4*)&Qs[tr + 16][kk];
#pragma unroll
      for (int j = 0; j < 4; ++j) {
        float4 bb = *(const float4*)&Ks[tc + 16 * j][kk];
        sacc[0][j] = fmaf(a0.x, bb.x, sacc[0][j]);
        sacc[0][j] = fmaf(a0.y, bb.y, sacc[0][j]);
        sacc[0][j] = fmaf(a0.z, bb.z, sacc[0][j]);
        sacc[0][j] = fmaf(a0.w, bb.w, sacc[0][j]);
        sacc[1][j] = fmaf(a1.x, bb.x, sacc[1][j]);
        sacc[1][j] = fmaf(a1.y, bb.y, sacc[1][j]);
        sacc[1][j] = fmaf(a1.z, bb.z, sacc[1][j]);
        sacc[1][j] = fmaf(a1.w, bb.w, sacc[1][j]);
      }
    }
#pragma unroll
    for (int i = 0; i < 2; ++i)
#pragma unroll
      for (int j = 0; j < 4; ++j)
        Ss[tr + 16 * i][tc + 16 * j] = sacc[i][j] * ATT_SCALE;
    __syncthreads();
#pragma unroll
    for (int i = 0; i < 8; ++i) {
      int idx = t + 256 * i;
      int r = idx >> 5, c4 = (idx & 31) * 4;
      *(float4*)&Ks[r][c4] = *(const float4*)&v[(long)(k0 + r) * vs + h * HD + c4];
    }
    float m4[4] = {-1e30f, -1e30f, -1e30f, -1e30f};
#pragma unroll
    for (int kk = 0; kk < 64; kk += 4) {
      m4[0] = fmaxf(m4[0], Ss[pr][kk]);
      m4[1] = fmaxf(m4[1], Ss[pr][kk + 1]);
      m4[2] = fmaxf(m4[2], Ss[pr][kk + 2]);
      m4[3] = fmaxf(m4[3], Ss[pr][kk + 3]);
    }
    float mt = fmaxf(fmaxf(m4[0], m4[1]), fmaxf(m4[2], m4[3]));
    float mnew  = fmaxf(m_run, mt);
    float alpha = __expf(m_run - mnew);
    float ps[4] = {0, 0, 0, 0};
#pragma unroll
    for (int kk = 0; kk < 64; kk += 4) {
      ps[0] += __expf(Ss[pr][kk] - mnew);
      ps[1] += __expf(Ss[pr][kk + 1] - mnew);
      ps[2] += __expf(Ss[pr][kk + 2] - mnew);
      ps[3] += __expf(Ss[pr][kk + 3] - mnew);
    }
    float psum = (ps[0] + ps[1]) + (ps[2] + ps[3]);
    float p8[8];
#pragma unroll
    for (int m2 = 0; m2 < 8; ++m2) p8[m2] = __expf(Ss[pr][kbase + m2] - mnew);
    l_run = l_run * alpha + psum;
    m_run = mnew;
#pragma unroll
    for (int jj = 0; jj < 4; ++jj)
#pragma unroll
      for (int m = 0; m < 4; ++m) pacc[jj][m] *= alpha;
    __syncthreads();
#pragma unroll
    for (int m2 = 0; m2 < 8; ++m2) Ss[pr][kbase + m2] = p8[m2];
    __syncthreads();
#pragma unroll 8
    for (int kk = 0; kk < 64; ++kk) {
      float p = Ss[pr][kk];
#pragma unroll
      for (int jj = 0; jj < 4; ++jj) {
        float4 vv = *(const float4*)&Ks[kk][pc + 32 * jj];
        pacc[jj][0] = fmaf(p, vv.x, pacc[jj][0]);
        pacc[jj][1] = fmaf(p, vv.y, pacc[jj][1]);
        pacc[jj][2] = fmaf(p, vv.z, pacc[jj][2]);
        pacc[jj][3] = fmaf(p, vv.w, pacc[jj][3]);
      }
    }
  }
  float inv = 1.f / l_run;
  long obase = (long)(q0 + pr) * D_MODEL + h * HD;
#pragma unroll
  for (int jj = 0; jj < 4; ++jj) {
    ushort4 ov;
    ov.x = f2bf(pacc[jj][0] * inv);
    ov.y = f2bf(pacc[jj][1] * inv);
    ov.z = f2bf(pacc[jj][2] * inv);
    ov.w = f2bf(pacc[jj][3] * inv);
    *(ushort4*)&o[obase + pc + 32 * jj] = ov;
  }
}

// ---------------------------------------------------------------------------
extern "C" void kernel_launch(void* const* d_in, const int* in_sizes, int n_in,
                              void* d_out, int out_size, void* d_ws, size_t ws_size,
                              hipStream_t stream) {
  const float* x      = (const float*)d_in[0];
  const float* ctx    = (const float*)d_in[1];
  const float* t_mod  = (const float*)d_in[2];
  const float* fcos   = (const float*)d_in[3];
  const float* fsin   = (const float*)d_in[4];
  const float* sa_wq = (const float*)d_in[5];  const float* sa_bq = (const float*)d_in[6];
  const float* sa_wk = (const float*)d_in[7];  const float* sa_bk = (const float*)d_in[8];
  const float* sa_wv = (const float*)d_in[9];  const float* sa_bv = (const float*)d_in[10];
  const float* sa_wo = (const float*)d_in[11]; const float* sa_bo = (const float*)d_in[12];
  const float* sa_nq = (const float*)d_in[13]; const float* sa_nk = (const float*)d_in[14];
  const float* ca_wq = (const float*)d_in[15]; const float* ca_bq = (const float*)d_in[16];
  const float* ca_wk = (const float*)d_in[17]; const float* ca_bk = (const float*)d_in[18];
  const float* ca_wv = (const float*)d_in[19]; const float* ca_bv = (const float*)d_in[20];
  const float* ca_wo = (const float*)d_in[21]; const float* ca_bo = (const float*)d_in[22];
  const float* ca_nq = (const float*)d_in[23]; const float* ca_nk = (const float*)d_in[24];
  const float* n3w = (const float*)d_in[25]; const float* n3b = (const float*)d_in[26];
  const float* w1 = (const float*)d_in[27]; const float* b1 = (const float*)d_in[28];
  const float* w2 = (const float*)d_in[29]; const float* b2 = (const float*)d_in[30];
  const float* modulation = (const float*)d_in[31];
  (void)in_sizes; (void)n_in; (void)out_size; (void)ws_size;

  float* out = (float*)d_out;
  char*  wsb = (char*)d_ws;
  const long TD = (long)T_TOK * D_MODEL;

  // ---- workspace layout (bytes, all 256-aligned) ----
  float*  modbuf  = (float*)(wsb + 0);                    //   221,184
  float*  biascat = (float*)(wsb + 221184);               //    30,720  (4608 qkv | 3072 kv)
  ushort* wscr    = (ushort*)(wsb + 251904);              // 27,525,120 (weight scratch, reused)
  ushort* inp     = (ushort*)(wsb + 27777024);            //  9,437,184 (T*D bf16)
  ushort* ctxb    = (ushort*)(wsb + 37214208);            //  1,572,864 (Tc*D bf16)
  char*   R       = wsb + 38787072;                       // 56,623,104 (multi-use region)
  ushort* attb    = (ushort*)(wsb + 95410176);            //  9,437,184 (T*D bf16)
  float*  x1      = (float*)(wsb + 104847360);            // 18,874,368
  float*  x2      = (float*)(wsb + 123721728);            // 18,874,368  (ends ~142.6 MB)

  float*  qkvb = (float*)R;                       // self: T x 4608 fp32
  float*  qc   = (float*)R;                       // cross: T x 1536 fp32
  float*  kvc  = (float*)(R + 18874368);          // cross: Tc x 3072 fp32
  ushort* hb   = (ushort*)R;                      // mlp:  T x FF bf16 (55.05 MB)

  dim3 b256(256);
  dim3 gT(T_TOK);
  dim3 gattn(T_TOK / 32, NH);
  const long WQ = (long)D_MODEL * D_MODEL;  // 1536*1536 elements

  // modulation + bias concat + ctx bf16
  mod_kernel<<<dim3((FRAMES * 6 * D_MODEL + 255) / 256), b256, 0, stream>>>(modulation, t_mod, modbuf);
  hipMemcpyAsync(biascat + 0,    sa_bq, 6144, hipMemcpyDeviceToDevice, stream);
  hipMemcpyAsync(biascat + 1536, sa_bk, 6144, hipMemcpyDeviceToDevice, stream);
  hipMemcpyAsync(biascat + 3072, sa_bv, 6144, hipMemcpyDeviceToDevice, stream);
  hipMemcpyAsync(biascat + 4608, ca_bk, 6144, hipMemcpyDeviceToDevice, stream);
  hipMemcpyAsync(biascat + 6144, ca_bv, 6144, hipMemcpyDeviceToDevice, stream);
  cvt_bf16_kernel<<<dim3(TC * D_MODEL / 4 / 256), b256, 0, stream>>>(ctx, ctxb, TC * D_MODEL / 4);

  dim3 gw(D_MODEL / 64, D_MODEL / 64);  // 24x24 for 1536x1536 weights

  // ===== self-attention branch =====
  ln_mod_kernel<<<gT, b256, 0, stream>>>(x, modbuf, 0, 1, inp);
  wconv_kernel<<<gw, b256, 0, stream>>>(sa_wq, wscr + 0 * WQ, D_MODEL, D_MODEL);
  wconv_kernel<<<gw, b256, 0, stream>>>(sa_wk, wscr + 1 * WQ, D_MODEL, D_MODEL);
  wconv_kernel<<<gw, b256, 0, stream>>>(sa_wv, wscr + 2 * WQ, D_MODEL, D_MODEL);
  mgemm_kernel<0><<<dim3(4608 / 128, T_TOK / 128), b256, 0, stream>>>(
      inp, wscr, biascat, nullptr, nullptr, 0, qkvb, T_TOK, 4608, D_MODEL, 4608);
  rms_kernel<true><<<gT, b256, 0, stream>>>(qkvb, 4608, sa_nq, fcos, fsin);
  rms_kernel<true><<<gT, b256, 0, stream>>>(qkvb + 1536, 4608, sa_nk, fcos, fsin);
  attn_kernel<true><<<gattn, b256, 0, stream>>>(qkvb, 4608, qkvb + 1536, 4608, qkvb + 3072, 4608, attb, T_TOK);
  wconv_kernel<<<gw, b256, 0, stream>>>(sa_wo, wscr, D_MODEL, D_MODEL);
  mgemm_kernel<2><<<dim3(D_MODEL / 128, T_TOK / 128), b256, 0, stream>>>(
      attb, wscr, sa_bo, x, modbuf, 2, x1, T_TOK, D_MODEL, D_MODEL, D_MODEL);

  // ===== cross-attention branch =====
  ln_affine_kernel<<<gT, b256, 0, stream>>>(x1, n3w, n3b, inp);
  wconv_kernel<<<gw, b256, 0, stream>>>(ca_wq, wscr, D_MODEL, D_MODEL);
  mgemm_kernel<0><<<dim3(D_MODEL / 128, T_TOK / 128), b256, 0, stream>>>(
      inp, wscr, ca_bq, nullptr, nullptr, 0, qc, T_TOK, D_MODEL, D_MODEL, D_MODEL);
  rms_kernel<false><<<gT, b256, 0, stream>>>(qc, 1536, ca_nq, nullptr, nullptr);
  wconv_kernel<<<gw, b256, 0, stream>>>(ca_wk, wscr + 0 * WQ, D_MODEL, D_MODEL);
  wconv_kernel<<<gw, b256, 0, stream>>>(ca_wv, wscr + 1 * WQ, D_MODEL, D_MODEL);
  mgemm_kernel<0><<<dim3(3072 / 128, TC / 128), b256, 0, stream>>>(
      ctxb, wscr, biascat + 4608, nullptr, nullptr, 0, kvc, TC, 3072, D_MODEL, 3072);
  rms_kernel<false><<<dim3(TC), b256, 0, stream>>>(kvc, 3072, ca_nk, nullptr, nullptr);
  attn_kernel<false><<<gattn, b256, 0, stream>>>(qc, 1536, kvc, 3072, kvc + 1536, 3072, attb, TC);
  wconv_kernel<<<gw, b256, 0, stream>>>(ca_wo, wscr, D_MODEL, D_MODEL);
  mgemm_kernel<3><<<dim3(D_MODEL / 128, T_TOK / 128), b256, 0, stream>>>(
      attb, wscr, ca_bo, x1, nullptr, 0, x2, T_TOK, D_MODEL, D_MODEL, D_MODEL);

  // ===== MLP branch =====
  ln_mod_kernel<<<gT, b256, 0, stream>>>(x2, modbuf, 3, 4, inp);
  wconv_kernel<<<dim3(FF_DIM / 64, D_MODEL / 64), b256, 0, stream>>>(w1, wscr, D_MODEL, FF_DIM);
  mgemm_kernel<1><<<dim3(FF_DIM / 128, T_TOK / 128), b256, 0, stream>>>(
      inp, wscr, b1, nullptr, nullptr, 0, hb, T_TOK, FF_DIM, D_MODEL, FF_DIM);
  wconv_kernel<<<dim3(D_MODEL / 64, FF_DIM / 64), b256, 0, stream>>>(w2, wscr, FF_DIM, D_MODEL);
  mgemm_kernel<2><<<dim3(D_MODEL / 128, T_TOK / 128), b256, 0, stream>>>(
      hb, wscr, b2, x2, modbuf, 5, out, T_TOK, D_MODEL, FF_DIM, D_MODEL);
}

// Round 3
// 1234.689 us; speedup vs baseline: 5.3569x; 1.7658x over previous
//
#include <hip/hip_runtime.h>
#include <cmath>

#define DEV __device__ __forceinline__

constexpr int T_TOK   = 3072;
constexpr int D_MODEL = 1536;
constexpr int FRAMES  = 6;
constexpr int NH      = 12;
constexpr int HD      = 128;
constexpr int FF_DIM  = 8960;
constexpr int TC      = 512;
constexpr float EPS_F = 1e-6f;
constexpr float ATT_SCALE = 0.08838834764831845f; // 1/sqrt(128)

typedef short bf16x8 __attribute__((ext_vector_type(8)));
typedef float f32x4  __attribute__((ext_vector_type(4)));

DEV ushort f2bf(float f) {
  unsigned u = __builtin_bit_cast(unsigned, f);
  unsigned r = u + 0x7fff + ((u >> 16) & 1);
  return (ushort)(r >> 16);
}

DEV void gload16(const void* g, void* l) {
  __builtin_amdgcn_global_load_lds(
      (const __attribute__((address_space(1))) void*)g,
      (__attribute__((address_space(3))) void*)l, 16, 0, 0);
}

// ---------------------------------------------------------------------------
__global__ __launch_bounds__(256) void mod_kernel(
    const float* __restrict__ modulation, const float* __restrict__ t_mod,
    float* __restrict__ modbuf) {
  int i = blockIdx.x * 256 + threadIdx.x;
  if (i >= FRAMES * 6 * D_MODEL) return;
  int d  = i % D_MODEL;
  int mi = (i / D_MODEL) % 6;
  modbuf[i] = modulation[mi * D_MODEL + d] + t_mod[i];
}

// fp32 -> bf16 elementwise (n4 = count/4)
__global__ __launch_bounds__(256) void cvt_bf16_kernel(
    const float* __restrict__ in, ushort* __restrict__ out, int n4) {
  int i = blockIdx.x * 256 + threadIdx.x;
  if (i >= n4) return;
  float4 v = ((const float4*)in)[i];
  ushort4 o;
  o.x = f2bf(v.x); o.y = f2bf(v.y); o.z = f2bf(v.z); o.w = f2bf(v.w);
  ((ushort4*)out)[i] = o;
}

// W(K,N) fp32 -> Wt(N,K) bf16. grid (N/64, K/64), block 256.
__global__ __launch_bounds__(256) void wconv_kernel(
    const float* __restrict__ W, ushort* __restrict__ Wt, int K, int N) {
  __shared__ float tile[64][65];
  const int k0 = blockIdx.y * 64, n0 = blockIdx.x * 64;
  const int t = threadIdx.x;
  const int r = t >> 4, c4 = (t & 15) * 4;
#pragma unroll
  for (int i = 0; i < 4; ++i) {
    float4 v = *(const float4*)&W[(long)(k0 + r + 16 * i) * N + n0 + c4];
    tile[r + 16 * i][c4 + 0] = v.x; tile[r + 16 * i][c4 + 1] = v.y;
    tile[r + 16 * i][c4 + 2] = v.z; tile[r + 16 * i][c4 + 3] = v.w;
  }
  __syncthreads();
  const int orow = t >> 5, oc2 = (t & 31) * 2;
#pragma unroll
  for (int j = 0; j < 8; ++j) {
    int nrow = orow + 8 * j;
    ushort2 o;
    o.x = f2bf(tile[oc2][nrow]);
    o.y = f2bf(tile[oc2 + 1][nrow]);
    *(ushort2*)&Wt[(long)(n0 + nrow) * K + k0 + oc2] = o;
  }
}

// transpose fp32 strided slice [Tv][1536] -> bf16 Vt[1536][Tv]. grid (Tv/64, 1536/64)
__global__ __launch_bounds__(256) void vtrans_kernel(
    const float* __restrict__ V, int stride, int Tv, ushort* __restrict__ Vt) {
  __shared__ float tile[64][65];
  const int t0 = blockIdx.x * 64, d0 = blockIdx.y * 64;
  const int t = threadIdx.x;
  const int r = t >> 4, c4 = (t & 15) * 4;
#pragma unroll
  for (int i = 0; i < 4; ++i) {
    float4 v = *(const float4*)&V[(long)(t0 + r + 16 * i) * stride + d0 + c4];
    tile[r + 16 * i][c4 + 0] = v.x; tile[r + 16 * i][c4 + 1] = v.y;
    tile[r + 16 * i][c4 + 2] = v.z; tile[r + 16 * i][c4 + 3] = v.w;
  }
  __syncthreads();
  const int od = t >> 2, tc = (t & 3) * 16;
#pragma unroll
  for (int j4 = 0; j4 < 4; ++j4) {
    ushort4 o;
    o.x = f2bf(tile[tc + j4 * 4 + 0][od]);
    o.y = f2bf(tile[tc + j4 * 4 + 1][od]);
    o.z = f2bf(tile[tc + j4 * 4 + 2][od]);
    o.w = f2bf(tile[tc + j4 * 4 + 3][od]);
    *(ushort4*)&Vt[(long)(d0 + od) * Tv + t0 + tc + j4 * 4] = o;
  }
}

// ---------------------------------------------------------------------------
DEV void block_reduce2(float& s, float& s2, float* red, int t) {
  int lane = t & 63, w = t >> 6;
#pragma unroll
  for (int o = 32; o > 0; o >>= 1) {
    s  += __shfl_down(s,  o, 64);
    s2 += __shfl_down(s2, o, 64);
  }
  if (lane == 0) { red[w] = s; red[4 + w] = s2; }
  __syncthreads();
  s  = (red[0] + red[1]) + (red[2] + red[3]);
  s2 = (red[4] + red[5]) + (red[6] + red[7]);
}

// LN (no affine) then y*(1+sc)+sh, bf16 output
__global__ __launch_bounds__(256) void ln_mod_kernel(
    const float* __restrict__ x, const float* __restrict__ modbuf,
    int ish, int isc, ushort* __restrict__ out) {
  __shared__ float red[8];
  int row = blockIdx.x, t = threadIdx.x;
  const float* xr = x + (long)row * D_MODEL;
  float vals[6];
  float s = 0.f, s2 = 0.f;
#pragma unroll
  for (int i = 0; i < 6; ++i) {
    float v = xr[t + 256 * i];
    vals[i] = v; s += v; s2 += v * v;
  }
  block_reduce2(s, s2, red, t);
  float mean = s * (1.f / D_MODEL);
  float var  = s2 * (1.f / D_MODEL) - mean * mean;
  float rs   = 1.f / sqrtf(var + EPS_F);
  const float* mb = modbuf + (long)(row >> 9) * 6 * D_MODEL;
#pragma unroll
  for (int i = 0; i < 6; ++i) {
    int d = t + 256 * i;
    float y = (vals[i] - mean) * rs;
    out[(long)row * D_MODEL + d] = f2bf(y * (1.f + mb[isc * D_MODEL + d]) + mb[ish * D_MODEL + d]);
  }
}

// LN with affine w,b, bf16 output
__global__ __launch_bounds__(256) void ln_affine_kernel(
    const float* __restrict__ x, const float* __restrict__ w,
    const float* __restrict__ b, ushort* __restrict__ out) {
  __shared__ float red[8];
  int row = blockIdx.x, t = threadIdx.x;
  const float* xr = x + (long)row * D_MODEL;
  float vals[6];
  float s = 0.f, s2 = 0.f;
#pragma unroll
  for (int i = 0; i < 6; ++i) {
    float v = xr[t + 256 * i];
    vals[i] = v; s += v; s2 += v * v;
  }
  block_reduce2(s, s2, red, t);
  float mean = s * (1.f / D_MODEL);
  float var  = s2 * (1.f / D_MODEL) - mean * mean;
  float rs   = 1.f / sqrtf(var + EPS_F);
#pragma unroll
  for (int i = 0; i < 6; ++i) {
    int d = t + 256 * i;
    float y = (vals[i] - mean) * rs;
    out[(long)row * D_MODEL + d] = f2bf(y * w[d] + b[d]);
  }
}

// RMS norm over D of strided fp32 rows -> packed bf16 [rows][D_MODEL]; optional RoPE
template <bool ROPE>
__global__ __launch_bounds__(256) void rmsbf_kernel(
    const float* __restrict__ in, int stride, const float* __restrict__ w,
    const float* __restrict__ cosb, const float* __restrict__ sinb,
    ushort* __restrict__ out) {
  __shared__ float red[8];
  int row = blockIdx.x, t = threadIdx.x;
  const float* xr = in + (long)row * stride;
  float vals[6];
  float s2 = 0.f, dummy = 0.f;
#pragma unroll
  for (int i = 0; i < 6; ++i) {
    float v = xr[t + 256 * i];
    vals[i] = v; s2 += v * v;
  }
  block_reduce2(s2, dummy, red, t);
  float rs = 1.f / sqrtf(s2 * (1.f / D_MODEL) + EPS_F);
  ushort* orow = out + (long)row * D_MODEL;
  if (ROPE) {
#pragma unroll
    for (int pi = 0; pi < 3; ++pi) {
      int p = t + 256 * pi;            // 0..767
      int hh = p >> 6, ii = p & 63;
      int d0 = hh * HD + 2 * ii;
      float a = xr[d0] * rs * w[d0];
      float b = xr[d0 + 1] * rs * w[d0 + 1];
      float c = cosb[(long)row * 64 + ii];
      float sn = sinb[(long)row * 64 + ii];
      ushort2 o;
      o.x = f2bf(a * c - b * sn);
      o.y = f2bf(a * sn + b * c);
      *(ushort2*)&orow[d0] = o;
    }
  } else {
#pragma unroll
    for (int i = 0; i < 6; ++i) {
      int d = t + 256 * i;
      orow[d] = f2bf(vals[i] * rs * w[d]);
    }
  }
}

// ---------------------------------------------------------------------------
// bf16 MFMA GEMM (m97 structure): C[M,N] = epi(A[M,K] @ Bt[N,K]^T + bias)
template <int EPI>
__global__ __launch_bounds__(256) void mgemm_kernel(
    const ushort* __restrict__ A, const ushort* __restrict__ Bt,
    const float* __restrict__ bias, const float* __restrict__ res,
    const float* __restrict__ modbuf, int gidx,
    void* __restrict__ Cout, int M, int N, int K, int ldc) {
  __shared__ ushort As[128 * 32];
  __shared__ ushort Bs[128 * 32];
  const int t = threadIdx.x;
  const int bm = blockIdx.y * 128, bn = blockIdx.x * 128;
  const int wave = t >> 6, lane = t & 63;
  const int wr = (wave >> 1) * 64, wc = (wave & 1) * 64;
  const int l15 = lane & 15, l4 = lane >> 4;

  f32x4 acc[4][4] = {};

  const int srow  = t >> 2;
  const int skoff = (t & 3) * 8;
  const ushort* Ag = A  + (long)(bm + srow) * K + skoff;
  const ushort* Bg = Bt + (long)(bn + srow) * K + skoff;
  ushort* Asl = As + t * 8;
  ushort* Bsl = Bs + t * 8;
  const long half = (long)64 * K;

  for (int k0 = 0; k0 < K; k0 += 32) {
    __syncthreads();
    gload16(Ag + k0, Asl);
    gload16(Ag + k0 + half, Asl + 2048);
    gload16(Bg + k0, Bsl);
    gload16(Bg + k0 + half, Bsl + 2048);
    asm volatile("s_waitcnt vmcnt(0)" ::: "memory");
    __syncthreads();
    bf16x8 af[4], bfr[4];
#pragma unroll
    for (int m = 0; m < 4; ++m)
      af[m] = *(const bf16x8*)&As[(wr + m * 16 + l15) * 32 + l4 * 8];
#pragma unroll
    for (int n = 0; n < 4; ++n)
      bfr[n] = *(const bf16x8*)&Bs[(wc + n * 16 + l15) * 32 + l4 * 8];
#pragma unroll
    for (int m = 0; m < 4; ++m)
#pragma unroll
      for (int n = 0; n < 4; ++n)
        acc[m][n] = __builtin_amdgcn_mfma_f32_16x16x32_bf16(af[m], bfr[n], acc[m][n], 0, 0, 0);
  }

#pragma unroll
  for (int m = 0; m < 4; ++m) {
#pragma unroll
    for (int r = 0; r < 4; ++r) {
      const int grow = bm + wr + m * 16 + l4 * 4 + r;
      const long rowoff = (long)grow * ldc;
      const float* mrow = nullptr;
      if (EPI == 2) mrow = modbuf + (long)((grow >> 9) * 6 + gidx) * D_MODEL;
#pragma unroll
      for (int n = 0; n < 4; ++n) {
        const int gcol = bn + wc + n * 16 + l15;
        float val = acc[m][n][r] + bias[gcol];
        if (EPI == 0) {
          ((float*)Cout)[rowoff + gcol] = val;
        } else if (EPI == 1) {
          float u = val;
          val = u / (1.f + __expf(-1.5957691216057308f * (u + 0.044715f * u * u * u)));
          ((ushort*)Cout)[rowoff + gcol] = f2bf(val);
        } else if (EPI == 2) {
          ((float*)Cout)[rowoff + gcol] = res[rowoff + gcol] + val * mrow[gcol];
        } else {
          ((float*)Cout)[rowoff + gcol] = res[rowoff + gcol] + val;
        }
      }
    }
  }
}

// ---------------------------------------------------------------------------
// bf16 MFMA flash attention.
// Qb,Kb: [T][D_MODEL] bf16 (head-major cols). Vt: [NH*HD][Tk] bf16 (transposed).
// Block: 128 q-rows x 1 head, 4 waves x 32 q-rows. KV tiles of 64.
// Frame-causal when CAUSAL (frame = 512 rows; QBLK=128 never straddles).
template <bool CAUSAL>
__global__ __launch_bounds__(256) void mattn_kernel(
    const ushort* __restrict__ Qb, const ushort* __restrict__ Kb,
    const ushort* __restrict__ Vt, ushort* __restrict__ O, int Tk) {
  __shared__ ushort Kl[64 * 136];   // row stride 136 elems (272 B)
  __shared__ ushort Vl[128 * 72];   // d-row stride 72 elems (144 B)
  __shared__ ushort Pl[4][32 * 72]; // per-wave P, q-row stride 72
  const int t = threadIdx.x;
  const int h = blockIdx.y;
  const int qb = CAUSAL ? (gridDim.x - 1 - blockIdx.x) : blockIdx.x;
  const int q0 = qb * 128;
  const int wave = t >> 6, lane = t & 63;
  const int l15 = lane & 15, l4 = lane >> 4;
  const int wq = wave * 32;
  const int kmax = CAUSAL ? (((q0 >> 9) + 1) << 9) : Tk;

  // Q fragments in registers: A[row=l15][k=l4*8..] per 16-row frag, 4 k-steps
  bf16x8 qf[2][4];
#pragma unroll
  for (int mf = 0; mf < 2; ++mf)
#pragma unroll
    for (int ks = 0; ks < 4; ++ks)
      qf[mf][ks] = *(const bf16x8*)&Qb[(long)(q0 + wq + mf * 16 + l15) * D_MODEL + h * HD + ks * 32 + l4 * 8];

  f32x4 ao[2][8] = {};
  float m_run[8], l_run[8];
#pragma unroll
  for (int i = 0; i < 8; ++i) { m_run[i] = -1e30f; l_run[i] = 0.f; }

  const ushort* Vh = Vt + (long)h * HD * Tk;
  ushort* Plw = &Pl[wave][0];

  for (int k0 = 0; k0 < kmax; k0 += 64) {
    __syncthreads();  // previous tile fully consumed
    {  // stage K tile: 64 rows x 128
      const int r = t >> 2, c0 = (t & 3) * 8;
      const ushort* src = Kb + (long)(k0 + r) * D_MODEL + h * HD + c0;
#pragma unroll
      for (int j = 0; j < 4; ++j)
        *(bf16x8*)&Kl[r * 136 + c0 + j * 32] = *(const bf16x8*)&src[j * 32];
    }
    {  // stage V tile transposed: 128 d-rows x 64 k
      const int d = t >> 1, c0 = (t & 1) * 32;
      const ushort* src = Vh + (long)d * Tk + k0 + c0;
#pragma unroll
      for (int j = 0; j < 4; ++j)
        *(bf16x8*)&Vl[d * 72 + c0 + j * 8] = *(const bf16x8*)&src[j * 8];
    }
    __syncthreads();

    // QK^T: S[32 q][64 k] per wave
    f32x4 s[2][4] = {};
#pragma unroll
    for (int n = 0; n < 4; ++n) {
      bf16x8 kf[4];
#pragma unroll
      for (int ks = 0; ks < 4; ++ks)
        kf[ks] = *(const bf16x8*)&Kl[(n * 16 + l15) * 136 + ks * 32 + l4 * 8];
#pragma unroll
      for (int mf = 0; mf < 2; ++mf)
#pragma unroll
        for (int ks = 0; ks < 4; ++ks)
          s[mf][n] = __builtin_amdgcn_mfma_f32_16x16x32_bf16(qf[mf][ks], kf[ks], s[mf][n], 0, 0, 0);
    }

    // online softmax (rows q = l4*4+r; cols spread over l15 lanes)
#pragma unroll
    for (int mf = 0; mf < 2; ++mf) {
      float mx[4], al[4], ps[4];
#pragma unroll
      for (int r = 0; r < 4; ++r)
        mx[r] = fmaxf(fmaxf(s[mf][0][r], s[mf][1][r]), fmaxf(s[mf][2][r], s[mf][3][r])) * ATT_SCALE;
#pragma unroll
      for (int off = 1; off < 16; off <<= 1)
#pragma unroll
        for (int r = 0; r < 4; ++r)
          mx[r] = fmaxf(mx[r], __shfl_xor(mx[r], off, 64));
#pragma unroll
      for (int r = 0; r < 4; ++r) {
        const int idx = mf * 4 + r;
        float mnew = fmaxf(m_run[idx], mx[r]);
        al[r] = __expf(m_run[idx] - mnew);
        m_run[idx] = mnew;
        float p0 = __expf(s[mf][0][r] * ATT_SCALE - mnew);
        float p1 = __expf(s[mf][1][r] * ATT_SCALE - mnew);
        float p2 = __expf(s[mf][2][r] * ATT_SCALE - mnew);
        float p3 = __expf(s[mf][3][r] * ATT_SCALE - mnew);
        s[mf][0][r] = p0; s[mf][1][r] = p1; s[mf][2][r] = p2; s[mf][3][r] = p3;
        ps[r] = (p0 + p1) + (p2 + p3);
      }
#pragma unroll
      for (int off = 1; off < 16; off <<= 1)
#pragma unroll
        for (int r = 0; r < 4; ++r)
          ps[r] += __shfl_xor(ps[r], off, 64);
#pragma unroll
      for (int r = 0; r < 4; ++r)
        l_run[mf * 4 + r] = l_run[mf * 4 + r] * al[r] + ps[r];
#pragma unroll
      for (int nd = 0; nd < 8; ++nd)
#pragma unroll
        for (int r = 0; r < 4; ++r)
          ao[mf][nd][r] *= al[r];
      // write P tile (bf16) for PV A-fragments
#pragma unroll
      for (int n = 0; n < 4; ++n)
#pragma unroll
        for (int r = 0; r < 4; ++r)
          Plw[(mf * 16 + l4 * 4 + r) * 72 + n * 16 + l15] = f2bf(s[mf][n][r]);
    }

    // PV: O[32 q][128 d] += P[32 q][64 k] @ V[64 k][128 d]
#pragma unroll
    for (int ks2 = 0; ks2 < 2; ++ks2) {
      bf16x8 paf[2];
#pragma unroll
      for (int mf = 0; mf < 2; ++mf)
        paf[mf] = *(const bf16x8*)&Plw[(mf * 16 + l15) * 72 + ks2 * 32 + l4 * 8];
#pragma unroll
      for (int nd = 0; nd < 8; ++nd) {
        bf16x8 vf = *(const bf16x8*)&Vl[(nd * 16 + l15) * 72 + ks2 * 32 + l4 * 8];
#pragma unroll
        for (int mf = 0; mf < 2; ++mf)
          ao[mf][nd] = __builtin_amdgcn_mfma_f32_16x16x32_bf16(paf[mf], vf, ao[mf][nd], 0, 0, 0);
      }
    }
  }

  // epilogue: O /= l, bf16 out
#pragma unroll
  for (int mf = 0; mf < 2; ++mf)
#pragma unroll
    for (int r = 0; r < 4; ++r) {
      float inv = 1.f / l_run[mf * 4 + r];
      long rb = (long)(q0 + wq + mf * 16 + l4 * 4 + r) * D_MODEL + h * HD + l15;
#pragma unroll
      for (int nd = 0; nd < 8; ++nd)
        O[rb + nd * 16] = f2bf(ao[mf][nd][r] * inv);
    }
}

// ---------------------------------------------------------------------------
extern "C" void kernel_launch(void* const* d_in, const int* in_sizes, int n_in,
                              void* d_out, int out_size, void* d_ws, size_t ws_size,
                              hipStream_t stream) {
  const float* x      = (const float*)d_in[0];
  const float* ctx    = (const float*)d_in[1];
  const float* t_mod  = (const float*)d_in[2];
  const float* fcos   = (const float*)d_in[3];
  const float* fsin   = (const float*)d_in[4];
  const float* sa_wq = (const float*)d_in[5];  const float* sa_bq = (const float*)d_in[6];
  const float* sa_wk = (const float*)d_in[7];  const float* sa_bk = (const float*)d_in[8];
  const float* sa_wv = (const float*)d_in[9];  const float* sa_bv = (const float*)d_in[10];
  const float* sa_wo = (const float*)d_in[11]; const float* sa_bo = (const float*)d_in[12];
  const float* sa_nq = (const float*)d_in[13]; const float* sa_nk = (const float*)d_in[14];
  const float* ca_wq = (const float*)d_in[15]; const float* ca_bq = (const float*)d_in[16];
  const float* ca_wk = (const float*)d_in[17]; const float* ca_bk = (const float*)d_in[18];
  const float* ca_wv = (const float*)d_in[19]; const float* ca_bv = (const float*)d_in[20];
  const float* ca_wo = (const float*)d_in[21]; const float* ca_bo = (const float*)d_in[22];
  const float* ca_nq = (const float*)d_in[23]; const float* ca_nk = (const float*)d_in[24];
  const float* n3w = (const float*)d_in[25]; const float* n3b = (const float*)d_in[26];
  const float* w1 = (const float*)d_in[27]; const float* b1 = (const float*)d_in[28];
  const float* w2 = (const float*)d_in[29]; const float* b2 = (const float*)d_in[30];
  const float* modulation = (const float*)d_in[31];
  (void)in_sizes; (void)n_in; (void)out_size; (void)ws_size;

  float* out = (float*)d_out;
  char*  wsb = (char*)d_ws;

  // ---- workspace layout (bytes) ----
  float*  modbuf  = (float*)(wsb + 0);            //    221,184
  float*  biascat = (float*)(wsb + 221184);       //     30,720
  ushort* wscr    = (ushort*)(wsb + 251904);      // 27,525,120 weight scratch
  ushort* inp     = (ushort*)(wsb + 27777024);    //  9,437,184 T*D bf16
  char*   R       = wsb + 37214208;               // 56,623,104 multi-use
  ushort* attb    = (ushort*)(wsb + 93837312);    //  9,437,184
  ushort* Qbb     = (ushort*)(wsb + 103274496);   //  9,437,184 self/cross Q bf16
  char*   KV      = wsb + 112711680;              // 18,874,368 self K/Vt bf16; later x1/x2
  char*   M       = wsb + 131586048;              //  3,145,728 ctxb | cross Kb + cross Vt
  // total 134,731,776 B

  float*  qkvb = (float*)R;                        // self: T x 4608 fp32
  float*  qc   = (float*)R;                        // cross: T x 1536 fp32
  float*  kvc  = (float*)(R + 18874368);           // cross: Tc x 3072 fp32
  ushort* hb   = (ushort*)R;                       // mlp:  T x FF bf16
  ushort* Kbb  = (ushort*)KV;                      // self K bf16 [T][D]
  ushort* Vtb  = (ushort*)(KV + 9437184);          // self Vt bf16 [1536][T]
  float*  x1   = (float*)KV;                       // residual after self (and after cross, in-place)
  ushort* ctxb = (ushort*)M;                       // ctx bf16 (dead after cross-KV gemm)
  ushort* Kbc  = (ushort*)M;                       // cross K bf16 [Tc][D] (overlays ctxb)
  ushort* Vtc  = (ushort*)(M + 1572864);           // cross Vt bf16 [1536][Tc]

  dim3 b256(256);
  dim3 gT(T_TOK);
  dim3 gattn(T_TOK / 128, NH);
  const long WQ = (long)D_MODEL * D_MODEL;

  mod_kernel<<<dim3((FRAMES * 6 * D_MODEL + 255) / 256), b256, 0, stream>>>(modulation, t_mod, modbuf);
  hipMemcpyAsync(biascat + 0,    sa_bq, 6144, hipMemcpyDeviceToDevice, stream);
  hipMemcpyAsync(biascat + 1536, sa_bk, 6144, hipMemcpyDeviceToDevice, stream);
  hipMemcpyAsync(biascat + 3072, sa_bv, 6144, hipMemcpyDeviceToDevice, stream);
  hipMemcpyAsync(biascat + 4608, ca_bk, 6144, hipMemcpyDeviceToDevice, stream);
  hipMemcpyAsync(biascat + 6144, ca_bv, 6144, hipMemcpyDeviceToDevice, stream);
  cvt_bf16_kernel<<<dim3(TC * D_MODEL / 4 / 256), b256, 0, stream>>>(ctx, ctxb, TC * D_MODEL / 4);

  dim3 gw(D_MODEL / 64, D_MODEL / 64);

  // ===== self-attention branch =====
  ln_mod_kernel<<<gT, b256, 0, stream>>>(x, modbuf, 0, 1, inp);
  wconv_kernel<<<gw, b256, 0, stream>>>(sa_wq, wscr + 0 * WQ, D_MODEL, D_MODEL);
  wconv_kernel<<<gw, b256, 0, stream>>>(sa_wk, wscr + 1 * WQ, D_MODEL, D_MODEL);
  wconv_kernel<<<gw, b256, 0, stream>>>(sa_wv, wscr + 2 * WQ, D_MODEL, D_MODEL);
  mgemm_kernel<0><<<dim3(4608 / 128, T_TOK / 128), b256, 0, stream>>>(
      inp, wscr, biascat, nullptr, nullptr, 0, qkvb, T_TOK, 4608, D_MODEL, 4608);
  rmsbf_kernel<true><<<gT, b256, 0, stream>>>(qkvb, 4608, sa_nq, fcos, fsin, Qbb);
  rmsbf_kernel<true><<<gT, b256, 0, stream>>>(qkvb + 1536, 4608, sa_nk, fcos, fsin, Kbb);
  vtrans_kernel<<<dim3(T_TOK / 64, D_MODEL / 64), b256, 0, stream>>>(qkvb + 3072, 4608, T_TOK, Vtb);
  mattn_kernel<true><<<gattn, b256, 0, stream>>>(Qbb, Kbb, Vtb, attb, T_TOK);
  wconv_kernel<<<gw, b256, 0, stream>>>(sa_wo, wscr, D_MODEL, D_MODEL);
  mgemm_kernel<2><<<dim3(D_MODEL / 128, T_TOK / 128), b256, 0, stream>>>(
      attb, wscr, sa_bo, x, modbuf, 2, x1, T_TOK, D_MODEL, D_MODEL, D_MODEL);

  // ===== cross-attention branch =====
  ln_affine_kernel<<<gT, b256, 0, stream>>>(x1, n3w, n3b, inp);
  wconv_kernel<<<gw, b256, 0, stream>>>(ca_wq, wscr, D_MODEL, D_MODEL);
  mgemm_kernel<0><<<dim3(D_MODEL / 128, T_TOK / 128), b256, 0, stream>>>(
      inp, wscr, ca_bq, nullptr, nullptr, 0, qc, T_TOK, D_MODEL, D_MODEL, D_MODEL);
  rmsbf_kernel<false><<<gT, b256, 0, stream>>>(qc, 1536, ca_nq, nullptr, nullptr, Qbb);
  wconv_kernel<<<gw, b256, 0, stream>>>(ca_wk, wscr + 0 * WQ, D_MODEL, D_MODEL);
  wconv_kernel<<<gw, b256, 0, stream>>>(ca_wv, wscr + 1 * WQ, D_MODEL, D_MODEL);
  mgemm_kernel<0><<<dim3(3072 / 128, TC / 128), b256, 0, stream>>>(
      ctxb, wscr, biascat + 4608, nullptr, nullptr, 0, kvc, TC, 3072, D_MODEL, 3072);
  rmsbf_kernel<false><<<dim3(TC), b256, 0, stream>>>(kvc, 3072, ca_nk, nullptr, nullptr, Kbc);
  vtrans_kernel<<<dim3(TC / 64, D_MODEL / 64), b256, 0, stream>>>(kvc + 1536, 3072, TC, Vtc);
  mattn_kernel<false><<<gattn, b256, 0, stream>>>(Qbb, Kbc, Vtc, attb, TC);
  wconv_kernel<<<gw, b256, 0, stream>>>(ca_wo, wscr, D_MODEL, D_MODEL);
  mgemm_kernel<3><<<dim3(D_MODEL / 128, T_TOK / 128), b256, 0, stream>>>(
      attb, wscr, ca_bo, x1, nullptr, 0, x1, T_TOK, D_MODEL, D_MODEL, D_MODEL);

  // ===== MLP branch =====
  ln_mod_kernel<<<gT, b256, 0, stream>>>(x1, modbuf, 3, 4, inp);
  wconv_kernel<<<dim3(FF_DIM / 64, D_MODEL / 64), b256, 0, stream>>>(w1, wscr, D_MODEL, FF_DIM);
  mgemm_kernel<1><<<dim3(FF_DIM / 128, T_TOK / 128), b256, 0, stream>>>(
      inp, wscr, b1, nullptr, nullptr, 0, hb, T_TOK, FF_DIM, D_MODEL, FF_DIM);
  wconv_kernel<<<dim3(D_MODEL / 64, FF_DIM / 64), b256, 0, stream>>>(w2, wscr, FF_DIM, D_MODEL);
  mgemm_kernel<2><<<dim3(D_MODEL / 128, T_TOK / 128), b256, 0, stream>>>(
      hb, wscr, b2, x1, modbuf, 5, out, T_TOK, D_MODEL, FF_DIM, D_MODEL);
}